// Round 8
// baseline (274.153 us; speedup 1.0000x reference)
//
#include <hip/hip_runtime.h>
#include <math.h>

#define B_ 16
#define N_ 576
#define C_ 768
#define NH 12
#define D_ 64
#define GW 24     // grid width/height (H = W = 24)
#define STR 68    // attention LDS row stride (ushorts)
#define QKV 2304  // fused QKV output row width
#define CSTR 136  // GEMM epilogue LDS row stride (ushorts)

typedef unsigned short u16;
typedef __bf16 bf16x8 __attribute__((ext_vector_type(8)));
typedef float f32x4 __attribute__((ext_vector_type(4)));

__device__ __forceinline__ u16 f2bf(float f) {
    unsigned u = __builtin_bit_cast(unsigned, f);
    unsigned r = (u + 0x7FFFu + ((u >> 16) & 1u)) >> 16;
    return (u16)r;
}
__device__ __forceinline__ float bf2f(u16 b) {
    unsigned u = ((unsigned)b) << 16;
    return __builtin_bit_cast(float, u);
}

// 8B-granular LDS frag read (STR=68 rows are only 8B-aligned)
__device__ __forceinline__ bf16x8 ldsF8u(const u16* p) {
    union { uint2 u[2]; bf16x8 v; } t;
    t.u[0] = *(const uint2*)p;
    t.u[1] = *(const uint2*)(p + 4);
    return t.v;
}
// 16B-aligned LDS frag read
__device__ __forceinline__ bf16x8 ldsF8a(const u16* p) {
    union { uint4 u; bf16x8 v; } t;
    t.u = *(const uint4*)p;
    return t.v;
}

// async global->LDS, 16B/lane; LDS dest = wave-uniform base + lane*16
__device__ __forceinline__ void gload16(const u16* g, u16* l) {
    __builtin_amdgcn_global_load_lds(
        (const __attribute__((address_space(1))) void*)g,
        (__attribute__((address_space(3))) void*)l,
        16, 0, 0);
}

// ---------------------------------------------------------------------------
// prep kernel: z<4 -> W^T bf16 transpose (32x32 tile); z==4 -> x fp32->bf16
// ---------------------------------------------------------------------------
__global__ __launch_bounds__(256)
void prep_kernel(const float* __restrict__ x,
                 const float* __restrict__ w0, const float* __restrict__ w1,
                 const float* __restrict__ w2, const float* __restrict__ w3,
                 u16* __restrict__ xb, u16* __restrict__ wt_base)
{
    const int tid = threadIdx.x;
    if (blockIdx.z == 4) {
        // conv_x: 576 blocks, 12 float4 per thread
        const int flat = blockIdx.y * 24 + blockIdx.x;
#pragma unroll
        for (int it = 0; it < 12; ++it) {
            int idx = flat * 3072 + it * 256 + tid;
            float4 v = ((const float4*)x)[idx];
            u16 o[4] = {f2bf(v.x), f2bf(v.y), f2bf(v.z), f2bf(v.w)};
            *(uint2*)&xb[(size_t)idx * 4] = *(const uint2*)o;
        }
        return;
    }
    const float* srcs[4] = {w0, w1, w2, w3};
    const float* src = srcs[blockIdx.z];
    u16* dst = wt_base + (size_t)blockIdx.z * C_ * C_;
    __shared__ float t[32][33];
    const int bx = blockIdx.x * 32, by = blockIdx.y * 32;
    const int tx = tid & 31, ty = tid >> 5;
#pragma unroll
    for (int i = 0; i < 32; i += 8)
        t[ty + i][tx] = src[(size_t)(by + ty + i) * C_ + bx + tx];
    __syncthreads();
#pragma unroll
    for (int i = 0; i < 32; i += 8)
        dst[(size_t)(bx + ty + i) * C_ + by + tx] = f2bf(t[tx][ty + i]);
}

// ---------------------------------------------------------------------------
// bf16 MFMA GEMM: 128x128 tile, BK=64, XOR-swizzled staging LDS.
// MFMA operands SWAPPED: mfma(bB, aA) -> lane l16 = row m, quad*4+r = col c.
// mode 0: fp32 [M][ldo] + bias, direct float4 stores.
// mode 1: bf16 [M][ldo] via LDS re-tile -> coalesced uint4 stores; Q scaled.
// ---------------------------------------------------------------------------
__global__ __launch_bounds__(256)
void mfma_gemm(const u16* __restrict__ A,
               const u16* __restrict__ BT,
               const float* __restrict__ bias,
               float* __restrict__ out,
               u16* __restrict__ outb,
               int ldo, int mode)
{
    const int K = C_;
    __shared__ __align__(16) u16 smem[128 * CSTR];   // 34816 B
    u16* As = smem;               // staging: 128 rows x 64 (16 KB)
    u16* Bs = smem + 128 * 64;    // staging: 128 rows x 64 (16 KB)
    const int tid = threadIdx.x;
    const int wave = tid >> 6, lane = tid & 63;
    const int quad = lane >> 4, l16 = lane & 15;
    const int wy = wave >> 1, wx = wave & 1;
    const int tm = blockIdx.y * 128, tn = blockIdx.x * 128;

    const int lr = lane >> 3;
    const int sc = ((lane & 7) ^ lr) * 8;

    f32x4 acc[4][4];
#pragma unroll
    for (int i = 0; i < 4; ++i)
#pragma unroll
        for (int j = 0; j < 4; ++j)
            acc[i][j] = (f32x4){0.f, 0.f, 0.f, 0.f};

    for (int k0 = 0; k0 < K; k0 += 64) {
        __syncthreads();
#pragma unroll
        for (int t = 0; t < 4; ++t) {
            const int rg = wave * 32 + t * 8;
            gload16(A  + (size_t)(tm + rg + lr) * K + k0 + sc, &As[rg * 64]);
            gload16(BT + (size_t)(tn + rg + lr) * K + k0 + sc, &Bs[rg * 64]);
        }
        __syncthreads();

#pragma unroll
        for (int kh = 0; kh < 2; ++kh) {
            bf16x8 aA[4], bB[4];
#pragma unroll
            for (int i = 0; i < 4; ++i) {
                const int s = (kh * 4 + quad) ^ (l16 & 7);
                aA[i] = ldsF8a(&As[(wy * 64 + i * 16 + l16) * 64 + s * 8]);
            }
#pragma unroll
            for (int j = 0; j < 4; ++j) {
                const int s = (kh * 4 + quad) ^ (l16 & 7);
                bB[j] = ldsF8a(&Bs[(wx * 64 + j * 16 + l16) * 64 + s * 8]);
            }
            // swapped operands: acc[i][j][r] = C[m = wy*64+i*16+l16]
            //                                   [c = wx*64+j*16+quad*4+r]
#pragma unroll
            for (int i = 0; i < 4; ++i)
#pragma unroll
                for (int j = 0; j < 4; ++j)
                    acc[i][j] = __builtin_amdgcn_mfma_f32_16x16x32_bf16(bB[j], aA[i], acc[i][j], 0, 0, 0);
        }
    }

    if (mode == 0) {
#pragma unroll
        for (int i = 0; i < 4; ++i) {
            const int m = tm + wy * 64 + i * 16 + l16;
#pragma unroll
            for (int j = 0; j < 4; ++j) {
                const int c = tn + wx * 64 + j * 16 + quad * 4;
                float4 bv = *(const float4*)&bias[c];
                float4 o;
                o.x = acc[i][j][0] + bv.x;
                o.y = acc[i][j][1] + bv.y;
                o.z = acc[i][j][2] + bv.z;
                o.w = acc[i][j][3] + bv.w;
                *(float4*)&out[(size_t)m * ldo + c] = o;
            }
        }
    } else {
        const float scale = (tn < C_) ? 0.125f : 1.0f;
        __syncthreads();   // staging reads done; reuse smem as C-tile
#pragma unroll
        for (int i = 0; i < 4; ++i) {
            const int ml = wy * 64 + i * 16 + l16;
#pragma unroll
            for (int j = 0; j < 4; ++j) {
                const int cl = wx * 64 + j * 16 + quad * 4;
                u16 o[4];
#pragma unroll
                for (int r = 0; r < 4; ++r) o[r] = f2bf(acc[i][j][r] * scale);
                *(uint2*)&smem[ml * CSTR + cl] = *(const uint2*)o;
            }
        }
        __syncthreads();
#pragma unroll
        for (int p = 0; p < 2; ++p) {
            const int idx = p * 256 + tid;
            const int row = idx >> 2, qq = idx & 3;    // quarter-row: 32 cols
            const u16* srcl = &smem[row * CSTR + qq * 32];
            u16* dstg = outb + (size_t)(tm + row) * ldo + tn + qq * 32;
#pragma unroll
            for (int t = 0; t < 4; ++t)
                *(uint4*)(dstg + t * 8) = *(const uint4*)(srcl + t * 8);
        }
    }
}

// ---------------------------------------------------------------------------
// fused: x<9 -> V-section transpose to vtb [B,NH,D,N]; x==9 -> pos stage 1
// (separable conv y-axis): T1[bh,ny,mx,d] = sum_my ey[my-ny] * V[my*GW+mx][d]
// ---------------------------------------------------------------------------
__global__ __launch_bounds__(256)
void tv_pos1_kernel(const u16* __restrict__ qkvb,
                    const float* __restrict__ pos_w,
                    u16* __restrict__ vtb,
                    float* __restrict__ T1)
{
    const int bh = blockIdx.y;
    const int b = bh / NH, h = bh % NH;
    const int tid = threadIdx.x;

    if (blockIdx.x < 9) {
        __shared__ u16 t[64 * 72];
        const int n0 = blockIdx.x * 64;
        const u16* src = qkvb + ((size_t)b * N_ + n0) * QKV + 2 * C_ + h * D_;
#pragma unroll
        for (int p = 0; p < 2; ++p) {
            int idx = p * 256 + tid;
            int r = idx >> 3, c = (idx & 7) << 3;
            *(uint4*)&t[r * 72 + c] = *(const uint4*)(src + (size_t)r * QKV + c);
        }
        __syncthreads();
        u16* dst = vtb + (size_t)bh * D_ * N_ + n0;
#pragma unroll
        for (int p = 0; p < 2; ++p) {
            int idx = p * 256 + tid;
            int dd = idx >> 3, n8 = (idx & 7) << 3;
            u16 o[8];
#pragma unroll
            for (int j = 0; j < 8; ++j) o[j] = t[(n8 + j) * 72 + dd];
            *(uint4*)(dst + (size_t)dd * N_ + n8) = *(const uint4*)o;
        }
        return;
    }

    // pos stage 1
    __shared__ float ey[47];
    const float w1 = pos_w[NH + h], w2 = pos_w[2 * NH + h];
    if (tid < 47) {
        float dy = (float)(tid - 23);
        ey[tid] = __expf(w1 * dy + w2 * dy * dy);
    }
    __syncthreads();
    if (tid >= 192) return;
    const int mx = tid >> 3, c = (tid & 7) << 3;
    const u16* src = qkvb + (size_t)b * N_ * QKV + 2 * C_ + h * D_ + c;

#pragma unroll
    for (int np = 0; np < 3; ++np) {
        float acc[8][8];
#pragma unroll
        for (int q = 0; q < 8; ++q)
#pragma unroll
            for (int j = 0; j < 8; ++j) acc[q][j] = 0.f;
        for (int my = 0; my < GW; ++my) {
            union { uint4 u; u16 s[8]; } d;
            d.u = *(const uint4*)(src + (size_t)(my * GW + mx) * QKV);
            float vf[8];
#pragma unroll
            for (int j = 0; j < 8; ++j) vf[j] = bf2f(d.s[j]);
#pragma unroll
            for (int q = 0; q < 8; ++q) {
                float e = ey[my - (np * 8 + q) + 23];
#pragma unroll
                for (int j = 0; j < 8; ++j) acc[q][j] += e * vf[j];
            }
        }
#pragma unroll
        for (int q = 0; q < 8; ++q) {
            const int ny = np * 8 + q;
            float* dst = T1 + (((size_t)bh * GW + ny) * GW + mx) * D_ + c;
            *(float4*)dst       = *(float4*)&acc[q][0];
            *(float4*)(dst + 4) = *(float4*)&acc[q][4];
        }
    }
}

// ---------------------------------------------------------------------------
// pos stage 2 (x-axis + gate blend): U[n,d] = sum_mx ex[mx-nx]*T1[ny,mx,d];
// aob[b,n,h*64+d] += g/(Sx[nx]*Sy[ny]) * U   (RMW after attn wrote content)
// ---------------------------------------------------------------------------
__global__ __launch_bounds__(256)
void pos_stage2_kernel(const float* __restrict__ T1,
                       const float* __restrict__ pos_w,
                       const float* __restrict__ gating,
                       u16* __restrict__ aob)
{
    const int bh = blockIdx.x;      // 192
    const int ny = blockIdx.y;      // 24
    const int b = bh / NH, h = bh % NH;
    const int tid = threadIdx.x;
    __shared__ float T1s[GW * D_];  // 1536 floats = 384 float4
    __shared__ float ex[47];
    __shared__ float SxA[GW];
    __shared__ float Sy;
    const float w0 = pos_w[h], w1 = pos_w[NH + h], w2 = pos_w[2 * NH + h];

    const float* tsrc = T1 + ((size_t)bh * GW + ny) * GW * D_;
#pragma unroll
    for (int i = 0; i < 2; ++i) {
        int idx = i * 256 + tid;
        if (idx < 384) ((float4*)T1s)[idx] = ((const float4*)tsrc)[idx];
    }
    if (tid < 47) {
        float dx = (float)(tid - 23);
        ex[tid] = __expf(w0 * dx + w2 * dx * dx);
    }
    if (tid == 192) {
        float s = 0.f;
        for (int my = 0; my < GW; ++my) {
            float dy = (float)(my - ny);
            s += __expf(w1 * dy + w2 * dy * dy);
        }
        Sy = s;
    }
    __syncthreads();
    if (tid < GW) {
        float s = 0.f;
        for (int mx = 0; mx < GW; ++mx) s += ex[mx - tid + 23];
        SxA[tid] = s;
    }
    __syncthreads();
    if (tid >= 192) return;
    const int nx = tid >> 3, c = (tid & 7) << 3;

    float acc[8];
#pragma unroll
    for (int j = 0; j < 8; ++j) acc[j] = 0.f;
    for (int mx = 0; mx < GW; ++mx) {
        float e = ex[mx - nx + 23];
        float4 t0 = *(float4*)&T1s[mx * D_ + c];
        float4 t1 = *(float4*)&T1s[mx * D_ + c + 4];
        acc[0] += e * t0.x; acc[1] += e * t0.y; acc[2] += e * t0.z; acc[3] += e * t0.w;
        acc[4] += e * t1.x; acc[5] += e * t1.y; acc[6] += e * t1.z; acc[7] += e * t1.w;
    }
    const float g = 1.f / (1.f + __expf(-gating[h]));
    const float sc = g / (SxA[nx] * Sy);
    const int n = ny * GW + nx;
    u16* dst = aob + ((size_t)b * N_ + n) * C_ + h * D_ + c;
    u16 cur[8];
    *(uint4*)cur = *(const uint4*)dst;
    u16 o[8];
#pragma unroll
    for (int j = 0; j < 8; ++j) o[j] = f2bf(bf2f(cur[j]) + sc * acc[j]);
    *(uint4*)dst = *(const uint4*)o;
}

// ---------------------------------------------------------------------------
// Flash-style MFMA attention, content stream only (pos handled separably).
// No online softmax (|s|<~4); register-double-buffered K/V staging.
// Writes (1-g)/l * O_c; pos_stage2 then adds the gated positional term.
// ---------------------------------------------------------------------------
__global__ __launch_bounds__(256)
void attn_kernel(const u16* __restrict__ qkvb,
                 const u16* __restrict__ vt,
                 const float* __restrict__ gating,
                 u16* __restrict__ ao)
{
    const int qt = blockIdx.x;
    const int bh = blockIdx.y;
    const int b = bh / NH, h = bh % NH;
    const int tid = threadIdx.x;
    const int wave = tid >> 6, lane = tid & 63;
    const int quad = lane >> 4, l16 = lane & 15;

    __shared__ u16 smem[3 * 64 * STR];   // 26.1 KB
    u16* Kt = smem;                  // K tile   [m'][d]
    u16* Vs = smem + 64 * STR;       // V^T tile [dd][m']
    u16* Pb = smem + 2 * 64 * STR;   // Q tile during prologue, then P tile

    const u16* qptr  = qkvb + ((size_t)b * N_ + qt * 64) * QKV + h * D_;
    const u16* kbase = qkvb + (size_t)b * N_ * QKV + C_ + h * D_;
    const u16* vbase = vt + (size_t)bh * D_ * N_;

    const int sr = tid >> 3;
    const int scol = (tid & 7) << 3;

#pragma unroll
    for (int p = 0; p < 2; ++p) {
        int r = p * 32 + sr;
        uint4 d = *(const uint4*)(qptr + (size_t)r * QKV + scol);
        *(uint2*)&Pb[r * STR + scol]     = make_uint2(d.x, d.y);
        *(uint2*)&Pb[r * STR + scol + 4] = make_uint2(d.z, d.w);
    }
    __syncthreads();

    const int arow = wave * 16 + l16;
    bf16x8 aq0 = ldsF8u(&Pb[arow * STR + quad * 8]);
    bf16x8 aq1 = ldsF8u(&Pb[arow * STR + 32 + quad * 8]);

    uint4 rk[2], rv[2];
    auto loadT = [&](int m0) {
#pragma unroll
        for (int p = 0; p < 2; ++p) {
            int r = p * 32 + sr;
            rk[p] = *(const uint4*)(kbase + (size_t)(m0 + r) * QKV + scol);
            rv[p] = *(const uint4*)(vbase + (size_t)r * N_ + m0 + scol);
        }
    };
    auto writeT = [&]() {
#pragma unroll
        for (int p = 0; p < 2; ++p) {
            int r = p * 32 + sr;
            *(uint2*)&Kt[r * STR + scol]     = make_uint2(rk[p].x, rk[p].y);
            *(uint2*)&Kt[r * STR + scol + 4] = make_uint2(rk[p].z, rk[p].w);
            *(uint2*)&Vs[r * STR + scol]     = make_uint2(rv[p].x, rv[p].y);
            *(uint2*)&Vs[r * STR + scol + 4] = make_uint2(rv[p].z, rv[p].w);
        }
    };

    loadT(0);

    f32x4 oc[4];
#pragma unroll
    for (int nt = 0; nt < 4; ++nt)
        oc[nt] = (f32x4){0.f, 0.f, 0.f, 0.f};
    float lrun[4] = {0.f, 0.f, 0.f, 0.f};

    for (int mt = 0; mt < 9; ++mt) {
        __syncthreads();
        writeT();
        __syncthreads();
        if (mt < 8) loadT((mt + 1) * 64);

        // S = Q @ K^T
        f32x4 s[4];
#pragma unroll
        for (int nt = 0; nt < 4; ++nt) {
            bf16x8 b0 = ldsF8u(&Kt[(nt * 16 + l16) * STR + quad * 8]);
            bf16x8 b1 = ldsF8u(&Kt[(nt * 16 + l16) * STR + 32 + quad * 8]);
            f32x4 z = (f32x4){0.f, 0.f, 0.f, 0.f};
            z = __builtin_amdgcn_mfma_f32_16x16x32_bf16(aq0, b0, z, 0, 0, 0);
            z = __builtin_amdgcn_mfma_f32_16x16x32_bf16(aq1, b1, z, 0, 0, 0);
            s[nt] = z;
        }

        // P = exp(S); per-lane partial row sums
#pragma unroll
        for (int r = 0; r < 4; ++r) {
            const int prow = (wave * 16 + quad * 4 + r) * STR;
            float e0 = __expf(s[0][r]);
            float e1 = __expf(s[1][r]);
            float e2 = __expf(s[2][r]);
            float e3 = __expf(s[3][r]);
            Pb[prow +  0 + l16] = f2bf(e0);
            Pb[prow + 16 + l16] = f2bf(e1);
            Pb[prow + 32 + l16] = f2bf(e2);
            Pb[prow + 48 + l16] = f2bf(e3);
            lrun[r] += (e0 + e1) + (e2 + e3);
        }
        asm volatile("s_waitcnt lgkmcnt(0)" ::: "memory");

        // O_c += P @ V
#pragma unroll
        for (int ks = 0; ks < 2; ++ks) {
            bf16x8 ap = ldsF8u(&Pb[arow * STR + ks * 32 + quad * 8]);
#pragma unroll
            for (int nt = 0; nt < 4; ++nt) {
                bf16x8 bv = ldsF8u(&Vs[(nt * 16 + l16) * STR + ks * 32 + quad * 8]);
                oc[nt] = __builtin_amdgcn_mfma_f32_16x16x32_bf16(ap, bv, oc[nt], 0, 0, 0);
            }
        }
    }

#pragma unroll
    for (int r = 0; r < 4; ++r) {
        lrun[r] += __shfl_xor(lrun[r], 1, 64);
        lrun[r] += __shfl_xor(lrun[r], 2, 64);
        lrun[r] += __shfl_xor(lrun[r], 4, 64);
        lrun[r] += __shfl_xor(lrun[r], 8, 64);
    }

    const float g = 1.f / (1.f + __expf(-gating[h]));
#pragma unroll
    for (int r = 0; r < 4; ++r) {
        const float sc = (1.f - g) / lrun[r];
        const int row = qt * 64 + wave * 16 + quad * 4 + r;
#pragma unroll
        for (int nt = 0; nt < 4; ++nt) {
            ao[((size_t)b * N_ + row) * C_ + h * D_ + nt * 16 + l16] =
                f2bf(oc[nt][r] * sc);
        }
    }
}

// ---------------------------------------------------------------------------
extern "C" void kernel_launch(void* const* d_in, const int* in_sizes, int n_in,
                              void* d_out, int out_size, void* d_ws, size_t ws_size,
                              hipStream_t stream)
{
    const float* x      = (const float*)d_in[0];
    const float* Wq     = (const float*)d_in[1];
    const float* Wk     = (const float*)d_in[2];
    const float* Wv     = (const float*)d_in[3];
    const float* Wproj  = (const float*)d_in[4];
    const float* bproj  = (const float*)d_in[5];
    const float* pos_w  = (const float*)d_in[6];
    const float* gating = (const float*)d_in[8];
    float* out = (float*)d_out;

    const size_t xe = (size_t)B_ * N_ * C_;        // 7,077,888
    const size_t we = (size_t)C_ * C_;             // 589,824
    const size_t qe = (size_t)B_ * N_ * QKV;       // 21,233,664
    u16* xb   = (u16*)d_ws;
    u16* wt   = xb + xe;            // packed [3072][768]: WqT|WkT|WvT|WprojT
    u16* qkvb = wt + 4 * we;        // [M][2304] bf16: Q | K | V
    u16* vtb  = qkvb + qe;          // [B,NH,D,N]
    u16* aob  = vtb + xe;           // [B,N,C] bf16 attn output
    float* T1 = (float*)(aob + xe); // [192][24][24][64] fp32 = 28.3 MB
    size_t need = (size_t)(3 * xe + 4 * we + qe) * sizeof(u16)
                + (size_t)B_ * NH * GW * GW * D_ * sizeof(float);  // ~118 MB
    if (ws_size < need) return;

    prep_kernel<<<dim3(24, 24, 5), 256, 0, stream>>>(x, Wq, Wk, Wv, Wproj, xb, wt);

    // fused QKV: bf16 [9216][2304]
    mfma_gemm<<<dim3(18, 72), 256, 0, stream>>>(xb, wt, nullptr, nullptr,
                                                qkvb, QKV, 1);
    tv_pos1_kernel<<<dim3(10, B_ * NH), 256, 0, stream>>>(qkvb, pos_w, vtb, T1);
    attn_kernel<<<dim3(9, B_ * NH), 256, 0, stream>>>(qkvb, vtb, gating, aob);
    pos_stage2_kernel<<<dim3(B_ * NH, GW), 256, 0, stream>>>(T1, pos_w, gating, aob);
    // projection: fp32 out + bias
    mfma_gemm<<<dim3(6, 72), 256, 0, stream>>>(aob, wt + 3 * we, bproj, out,
                                               nullptr, C_, 0);
}

// Round 9
// 260.995 us; speedup vs baseline: 1.0504x; 1.0504x over previous
//
#include <hip/hip_runtime.h>
#include <math.h>

#define B_ 16
#define N_ 576
#define C_ 768
#define NH 12
#define D_ 64
#define GW 24     // grid width/height (H = W = 24)
#define STR 68    // attention LDS row stride (ushorts)
#define QKV 2304  // fused QKV output row width

typedef unsigned short u16;
typedef __bf16 bf16x8 __attribute__((ext_vector_type(8)));
typedef float f32x4 __attribute__((ext_vector_type(4)));

__device__ __forceinline__ u16 f2bf(float f) {
    unsigned u = __builtin_bit_cast(unsigned, f);
    unsigned r = (u + 0x7FFFu + ((u >> 16) & 1u)) >> 16;
    return (u16)r;
}
__device__ __forceinline__ float bf2f(u16 b) {
    unsigned u = ((unsigned)b) << 16;
    return __builtin_bit_cast(float, u);
}

// 8B-granular LDS frag read (STR=68 rows are only 8B-aligned)
__device__ __forceinline__ bf16x8 ldsF8u(const u16* p) {
    union { uint2 u[2]; bf16x8 v; } t;
    t.u[0] = *(const uint2*)p;
    t.u[1] = *(const uint2*)(p + 4);
    return t.v;
}
// 16B-aligned LDS frag read
__device__ __forceinline__ bf16x8 ldsF8a(const u16* p) {
    union { uint4 u; bf16x8 v; } t;
    t.u = *(const uint4*)p;
    return t.v;
}

// async global->LDS, 16B/lane; LDS dest = wave-uniform base + lane*16
__device__ __forceinline__ void gload16(const u16* g, u16* l) {
    __builtin_amdgcn_global_load_lds(
        (const __attribute__((address_space(1))) void*)g,
        (__attribute__((address_space(3))) void*)l,
        16, 0, 0);
}

// ---------------------------------------------------------------------------
// prep kernel: z<4 -> W^T bf16 transpose (32x32 tile); z==4 -> x fp32->bf16
// ---------------------------------------------------------------------------
__global__ __launch_bounds__(256)
void prep_kernel(const float* __restrict__ x,
                 const float* __restrict__ w0, const float* __restrict__ w1,
                 const float* __restrict__ w2, const float* __restrict__ w3,
                 u16* __restrict__ xb, u16* __restrict__ wt_base)
{
    const int tid = threadIdx.x;
    if (blockIdx.z == 4) {
        const int flat = blockIdx.y * 24 + blockIdx.x;
#pragma unroll
        for (int it = 0; it < 12; ++it) {
            int idx = flat * 3072 + it * 256 + tid;
            float4 v = ((const float4*)x)[idx];
            u16 o[4] = {f2bf(v.x), f2bf(v.y), f2bf(v.z), f2bf(v.w)};
            *(uint2*)&xb[(size_t)idx * 4] = *(const uint2*)o;
        }
        return;
    }
    const float* srcs[4] = {w0, w1, w2, w3};
    const float* src = srcs[blockIdx.z];
    u16* dst = wt_base + (size_t)blockIdx.z * C_ * C_;
    __shared__ float t[32][33];
    const int bx = blockIdx.x * 32, by = blockIdx.y * 32;
    const int tx = tid & 31, ty = tid >> 5;
#pragma unroll
    for (int i = 0; i < 32; i += 8)
        t[ty + i][tx] = src[(size_t)(by + ty + i) * C_ + bx + tx];
    __syncthreads();
#pragma unroll
    for (int i = 0; i < 32; i += 8)
        dst[(size_t)(bx + ty + i) * C_ + by + tx] = f2bf(t[tx][ty + i]);
}

// ---------------------------------------------------------------------------
// bf16 MFMA GEMM: 64x128 tile (BM=64 for grid parallelism: 2592/864 blocks),
// BK=64, XOR-swizzled staging LDS (24 KB), 4 waves each computing 32x64 via
// 2x4 16x16x32 MFMAs.  acc[i][j][r] = C[row=quad*4+r][col=l16] (original
// operand order; R8's swapped-operand LDS epilogue regressed -> reverted).
// mode 0: fp32 [M][ldo] + bias; mode 1: bf16 [M][ldo], Q section scaled.
// ---------------------------------------------------------------------------
__global__ __launch_bounds__(256)
void mfma_gemm(const u16* __restrict__ A,
               const u16* __restrict__ BT,
               const float* __restrict__ bias,
               float* __restrict__ out,
               u16* __restrict__ outb,
               int ldo, int mode)
{
    const int K = C_;
    __shared__ __align__(16) u16 As[64 * 64];    //  8 KB
    __shared__ __align__(16) u16 Bs[128 * 64];   // 16 KB
    const int tid = threadIdx.x;
    const int wave = tid >> 6, lane = tid & 63;
    const int quad = lane >> 4, l16 = lane & 15;
    const int wy = wave >> 1, wx = wave & 1;     // wy: 32-row half, wx: 64-col half
    const int tm = blockIdx.y * 64, tn = blockIdx.x * 128;

    const int lr = lane >> 3;                    // row within 8-row staging group
    const int sc = ((lane & 7) ^ lr) * 8;        // swizzled source col (elems)

    f32x4 acc[2][4];
#pragma unroll
    for (int i = 0; i < 2; ++i)
#pragma unroll
        for (int j = 0; j < 4; ++j)
            acc[i][j] = (f32x4){0.f, 0.f, 0.f, 0.f};

    for (int k0 = 0; k0 < K; k0 += 64) {
        __syncthreads();
#pragma unroll
        for (int t = 0; t < 2; ++t) {            // A: 8 groups / 4 waves
            const int rg = wave * 16 + t * 8;
            gload16(A + (size_t)(tm + rg + lr) * K + k0 + sc, &As[rg * 64]);
        }
#pragma unroll
        for (int t = 0; t < 4; ++t) {            // B: 16 groups / 4 waves
            const int rg = wave * 32 + t * 8;
            gload16(BT + (size_t)(tn + rg + lr) * K + k0 + sc, &Bs[rg * 64]);
        }
        __syncthreads();

#pragma unroll
        for (int kh = 0; kh < 2; ++kh) {
            const int s = (kh * 4 + quad) ^ (l16 & 7);
            bf16x8 aA[2], bB[4];
#pragma unroll
            for (int i = 0; i < 2; ++i)
                aA[i] = ldsF8a(&As[(wy * 32 + i * 16 + l16) * 64 + s * 8]);
#pragma unroll
            for (int j = 0; j < 4; ++j)
                bB[j] = ldsF8a(&Bs[(wx * 64 + j * 16 + l16) * 64 + s * 8]);
#pragma unroll
            for (int i = 0; i < 2; ++i)
#pragma unroll
                for (int j = 0; j < 4; ++j)
                    acc[i][j] = __builtin_amdgcn_mfma_f32_16x16x32_bf16(aA[i], bB[j], acc[i][j], 0, 0, 0);
        }
    }

    if (mode == 0) {
#pragma unroll
        for (int i = 0; i < 2; ++i) {
#pragma unroll
            for (int r = 0; r < 4; ++r) {
                const int m = tm + wy * 32 + i * 16 + quad * 4 + r;
#pragma unroll
                for (int j = 0; j < 4; ++j) {
                    const int c = tn + wx * 64 + j * 16 + l16;
                    out[(size_t)m * ldo + c] = acc[i][j][r] + bias[c];
                }
            }
        }
    } else {
        const float scale = (tn < C_) ? 0.125f : 1.0f;
#pragma unroll
        for (int i = 0; i < 2; ++i) {
#pragma unroll
            for (int r = 0; r < 4; ++r) {
                const int m = tm + wy * 32 + i * 16 + quad * 4 + r;
#pragma unroll
                for (int j = 0; j < 4; ++j) {
                    const int c = tn + wx * 64 + j * 16 + l16;
                    outb[(size_t)m * ldo + c] = f2bf(acc[i][j][r] * scale);
                }
            }
        }
    }
}

// ---------------------------------------------------------------------------
// fused: x<9 -> V-section transpose to vtb [B,NH,D,N]; x==9 -> pos stage 1
// (separable conv y-axis): T1[bh,ny,mx,d] = sum_my ey[my-ny] * V[my*GW+mx][d]
// ---------------------------------------------------------------------------
__global__ __launch_bounds__(256)
void tv_pos1_kernel(const u16* __restrict__ qkvb,
                    const float* __restrict__ pos_w,
                    u16* __restrict__ vtb,
                    float* __restrict__ T1)
{
    const int bh = blockIdx.y;
    const int b = bh / NH, h = bh % NH;
    const int tid = threadIdx.x;

    if (blockIdx.x < 9) {
        __shared__ u16 t[64 * 72];
        const int n0 = blockIdx.x * 64;
        const u16* src = qkvb + ((size_t)b * N_ + n0) * QKV + 2 * C_ + h * D_;
#pragma unroll
        for (int p = 0; p < 2; ++p) {
            int idx = p * 256 + tid;
            int r = idx >> 3, c = (idx & 7) << 3;
            *(uint4*)&t[r * 72 + c] = *(const uint4*)(src + (size_t)r * QKV + c);
        }
        __syncthreads();
        u16* dst = vtb + (size_t)bh * D_ * N_ + n0;
#pragma unroll
        for (int p = 0; p < 2; ++p) {
            int idx = p * 256 + tid;
            int dd = idx >> 3, n8 = (idx & 7) << 3;
            u16 o[8];
#pragma unroll
            for (int j = 0; j < 8; ++j) o[j] = t[(n8 + j) * 72 + dd];
            *(uint4*)(dst + (size_t)dd * N_ + n8) = *(const uint4*)o;
        }
        return;
    }

    // pos stage 1
    __shared__ float ey[47];
    const float w1 = pos_w[NH + h], w2 = pos_w[2 * NH + h];
    if (tid < 47) {
        float dy = (float)(tid - 23);
        ey[tid] = __expf(w1 * dy + w2 * dy * dy);
    }
    __syncthreads();
    if (tid >= 192) return;
    const int mx = tid >> 3, c = (tid & 7) << 3;
    const u16* src = qkvb + (size_t)b * N_ * QKV + 2 * C_ + h * D_ + c;

#pragma unroll
    for (int np = 0; np < 3; ++np) {
        float acc[8][8];
#pragma unroll
        for (int q = 0; q < 8; ++q)
#pragma unroll
            for (int j = 0; j < 8; ++j) acc[q][j] = 0.f;
        for (int my = 0; my < GW; ++my) {
            union { uint4 u; u16 s[8]; } d;
            d.u = *(const uint4*)(src + (size_t)(my * GW + mx) * QKV);
            float vf[8];
#pragma unroll
            for (int j = 0; j < 8; ++j) vf[j] = bf2f(d.s[j]);
#pragma unroll
            for (int q = 0; q < 8; ++q) {
                float e = ey[my - (np * 8 + q) + 23];
#pragma unroll
                for (int j = 0; j < 8; ++j) acc[q][j] += e * vf[j];
            }
        }
#pragma unroll
        for (int q = 0; q < 8; ++q) {
            const int ny = np * 8 + q;
            float* dst = T1 + (((size_t)bh * GW + ny) * GW + mx) * D_ + c;
            *(float4*)dst       = *(float4*)&acc[q][0];
            *(float4*)(dst + 4) = *(float4*)&acc[q][4];
        }
    }
}

// ---------------------------------------------------------------------------
// pos stage 2 (x-axis + gate blend): U[n,d] = sum_mx ex[mx-nx]*T1[ny,mx,d];
// aob[b,n,h*64+d] += g/(Sx[nx]*Sy[ny]) * U   (RMW after attn wrote content)
// ---------------------------------------------------------------------------
__global__ __launch_bounds__(256)
void pos_stage2_kernel(const float* __restrict__ T1,
                       const float* __restrict__ pos_w,
                       const float* __restrict__ gating,
                       u16* __restrict__ aob)
{
    const int bh = blockIdx.x;      // 192
    const int ny = blockIdx.y;      // 24
    const int b = bh / NH, h = bh % NH;
    const int tid = threadIdx.x;
    __shared__ float T1s[GW * D_];  // 1536 floats = 384 float4
    __shared__ float ex[47];
    __shared__ float SxA[GW];
    __shared__ float Sy;
    const float w0 = pos_w[h], w1 = pos_w[NH + h], w2 = pos_w[2 * NH + h];

    const float* tsrc = T1 + ((size_t)bh * GW + ny) * GW * D_;
#pragma unroll
    for (int i = 0; i < 2; ++i) {
        int idx = i * 256 + tid;
        if (idx < 384) ((float4*)T1s)[idx] = ((const float4*)tsrc)[idx];
    }
    if (tid < 47) {
        float dx = (float)(tid - 23);
        ex[tid] = __expf(w0 * dx + w2 * dx * dx);
    }
    if (tid == 192) {
        float s = 0.f;
        for (int my = 0; my < GW; ++my) {
            float dy = (float)(my - ny);
            s += __expf(w1 * dy + w2 * dy * dy);
        }
        Sy = s;
    }
    __syncthreads();
    if (tid < GW) {
        float s = 0.f;
        for (int mx = 0; mx < GW; ++mx) s += ex[mx - tid + 23];
        SxA[tid] = s;
    }
    __syncthreads();
    if (tid >= 192) return;
    const int nx = tid >> 3, c = (tid & 7) << 3;

    float acc[8];
#pragma unroll
    for (int j = 0; j < 8; ++j) acc[j] = 0.f;
    for (int mx = 0; mx < GW; ++mx) {
        float e = ex[mx - nx + 23];
        float4 t0 = *(float4*)&T1s[mx * D_ + c];
        float4 t1 = *(float4*)&T1s[mx * D_ + c + 4];
        acc[0] += e * t0.x; acc[1] += e * t0.y; acc[2] += e * t0.z; acc[3] += e * t0.w;
        acc[4] += e * t1.x; acc[5] += e * t1.y; acc[6] += e * t1.z; acc[7] += e * t1.w;
    }
    const float g = 1.f / (1.f + __expf(-gating[h]));
    const float sc = g / (SxA[nx] * Sy);
    const int n = ny * GW + nx;
    u16* dst = aob + ((size_t)b * N_ + n) * C_ + h * D_ + c;
    u16 cur[8];
    *(uint4*)cur = *(const uint4*)dst;
    u16 o[8];
#pragma unroll
    for (int j = 0; j < 8; ++j) o[j] = f2bf(bf2f(cur[j]) + sc * acc[j]);
    *(uint4*)dst = *(const uint4*)o;
}

// ---------------------------------------------------------------------------
// Flash-style MFMA attention, content stream only (pos handled separably).
// No online softmax (|s|<~4); register-double-buffered K/V staging.
// Writes (1-g)/l * O_c; pos_stage2 then adds the gated positional term.
// ---------------------------------------------------------------------------
__global__ __launch_bounds__(256)
void attn_kernel(const u16* __restrict__ qkvb,
                 const u16* __restrict__ vt,
                 const float* __restrict__ gating,
                 u16* __restrict__ ao)
{
    const int qt = blockIdx.x;
    const int bh = blockIdx.y;
    const int b = bh / NH, h = bh % NH;
    const int tid = threadIdx.x;
    const int wave = tid >> 6, lane = tid & 63;
    const int quad = lane >> 4, l16 = lane & 15;

    __shared__ u16 smem[3 * 64 * STR];   // 26.1 KB
    u16* Kt = smem;                  // K tile   [m'][d]
    u16* Vs = smem + 64 * STR;       // V^T tile [dd][m']
    u16* Pb = smem + 2 * 64 * STR;   // Q tile during prologue, then P tile

    const u16* qptr  = qkvb + ((size_t)b * N_ + qt * 64) * QKV + h * D_;
    const u16* kbase = qkvb + (size_t)b * N_ * QKV + C_ + h * D_;
    const u16* vbase = vt + (size_t)bh * D_ * N_;

    const int sr = tid >> 3;
    const int scol = (tid & 7) << 3;

#pragma unroll
    for (int p = 0; p < 2; ++p) {
        int r = p * 32 + sr;
        uint4 d = *(const uint4*)(qptr + (size_t)r * QKV + scol);
        *(uint2*)&Pb[r * STR + scol]     = make_uint2(d.x, d.y);
        *(uint2*)&Pb[r * STR + scol + 4] = make_uint2(d.z, d.w);
    }
    __syncthreads();

    const int arow = wave * 16 + l16;
    bf16x8 aq0 = ldsF8u(&Pb[arow * STR + quad * 8]);
    bf16x8 aq1 = ldsF8u(&Pb[arow * STR + 32 + quad * 8]);

    uint4 rk[2], rv[2];
    auto loadT = [&](int m0) {
#pragma unroll
        for (int p = 0; p < 2; ++p) {
            int r = p * 32 + sr;
            rk[p] = *(const uint4*)(kbase + (size_t)(m0 + r) * QKV + scol);
            rv[p] = *(const uint4*)(vbase + (size_t)r * N_ + m0 + scol);
        }
    };
    auto writeT = [&]() {
#pragma unroll
        for (int p = 0; p < 2; ++p) {
            int r = p * 32 + sr;
            *(uint2*)&Kt[r * STR + scol]     = make_uint2(rk[p].x, rk[p].y);
            *(uint2*)&Kt[r * STR + scol + 4] = make_uint2(rk[p].z, rk[p].w);
            *(uint2*)&Vs[r * STR + scol]     = make_uint2(rv[p].x, rv[p].y);
            *(uint2*)&Vs[r * STR + scol + 4] = make_uint2(rv[p].z, rv[p].w);
        }
    };

    loadT(0);

    f32x4 oc[4];
#pragma unroll
    for (int nt = 0; nt < 4; ++nt)
        oc[nt] = (f32x4){0.f, 0.f, 0.f, 0.f};
    float lrun[4] = {0.f, 0.f, 0.f, 0.f};

    for (int mt = 0; mt < 9; ++mt) {
        __syncthreads();
        writeT();
        __syncthreads();
        if (mt < 8) loadT((mt + 1) * 64);

        // S = Q @ K^T
        f32x4 s[4];
#pragma unroll
        for (int nt = 0; nt < 4; ++nt) {
            bf16x8 b0 = ldsF8u(&Kt[(nt * 16 + l16) * STR + quad * 8]);
            bf16x8 b1 = ldsF8u(&Kt[(nt * 16 + l16) * STR + 32 + quad * 8]);
            f32x4 z = (f32x4){0.f, 0.f, 0.f, 0.f};
            z = __builtin_amdgcn_mfma_f32_16x16x32_bf16(aq0, b0, z, 0, 0, 0);
            z = __builtin_amdgcn_mfma_f32_16x16x32_bf16(aq1, b1, z, 0, 0, 0);
            s[nt] = z;
        }

        // P = exp(S); per-lane partial row sums
#pragma unroll
        for (int r = 0; r < 4; ++r) {
            const int prow = (wave * 16 + quad * 4 + r) * STR;
            float e0 = __expf(s[0][r]);
            float e1 = __expf(s[1][r]);
            float e2 = __expf(s[2][r]);
            float e3 = __expf(s[3][r]);
            Pb[prow +  0 + l16] = f2bf(e0);
            Pb[prow + 16 + l16] = f2bf(e1);
            Pb[prow + 32 + l16] = f2bf(e2);
            Pb[prow + 48 + l16] = f2bf(e3);
            lrun[r] += (e0 + e1) + (e2 + e3);
        }
        asm volatile("s_waitcnt lgkmcnt(0)" ::: "memory");

        // O_c += P @ V
#pragma unroll
        for (int ks = 0; ks < 2; ++ks) {
            bf16x8 ap = ldsF8u(&Pb[arow * STR + ks * 32 + quad * 8]);
#pragma unroll
            for (int nt = 0; nt < 4; ++nt) {
                bf16x8 bv = ldsF8u(&Vs[(nt * 16 + l16) * STR + ks * 32 + quad * 8]);
                oc[nt] = __builtin_amdgcn_mfma_f32_16x16x32_bf16(ap, bv, oc[nt], 0, 0, 0);
            }
        }
    }

#pragma unroll
    for (int r = 0; r < 4; ++r) {
        lrun[r] += __shfl_xor(lrun[r], 1, 64);
        lrun[r] += __shfl_xor(lrun[r], 2, 64);
        lrun[r] += __shfl_xor(lrun[r], 4, 64);
        lrun[r] += __shfl_xor(lrun[r], 8, 64);
    }

    const float g = 1.f / (1.f + __expf(-gating[h]));
#pragma unroll
    for (int r = 0; r < 4; ++r) {
        const float sc = (1.f - g) / lrun[r];
        const int row = qt * 64 + wave * 16 + quad * 4 + r;
#pragma unroll
        for (int nt = 0; nt < 4; ++nt) {
            ao[((size_t)b * N_ + row) * C_ + h * D_ + nt * 16 + l16] =
                f2bf(oc[nt][r] * sc);
        }
    }
}

// ---------------------------------------------------------------------------
extern "C" void kernel_launch(void* const* d_in, const int* in_sizes, int n_in,
                              void* d_out, int out_size, void* d_ws, size_t ws_size,
                              hipStream_t stream)
{
    const float* x      = (const float*)d_in[0];
    const float* Wq     = (const float*)d_in[1];
    const float* Wk     = (const float*)d_in[2];
    const float* Wv     = (const float*)d_in[3];
    const float* Wproj  = (const float*)d_in[4];
    const float* bproj  = (const float*)d_in[5];
    const float* pos_w  = (const float*)d_in[6];
    const float* gating = (const float*)d_in[8];
    float* out = (float*)d_out;

    const size_t xe = (size_t)B_ * N_ * C_;        // 7,077,888
    const size_t we = (size_t)C_ * C_;             // 589,824
    const size_t qe = (size_t)B_ * N_ * QKV;       // 21,233,664
    u16* xb   = (u16*)d_ws;
    u16* wt   = xb + xe;            // packed [3072][768]: WqT|WkT|WvT|WprojT
    u16* qkvb = wt + 4 * we;        // [M][2304] bf16: Q | K | V
    u16* vtb  = qkvb + qe;          // [B,NH,D,N]
    u16* aob  = vtb + xe;           // [B,N,C] bf16 attn output
    float* T1 = (float*)(aob + xe); // [192][24][24][64] fp32 = 28.3 MB
    size_t need = (size_t)(3 * xe + 4 * we + qe) * sizeof(u16)
                + (size_t)B_ * NH * GW * GW * D_ * sizeof(float);  // ~118 MB
    if (ws_size < need) return;

    prep_kernel<<<dim3(24, 24, 5), 256, 0, stream>>>(x, Wq, Wk, Wv, Wproj, xb, wt);

    // fused QKV: bf16 [9216][2304], 64x128 tiles -> 2592 blocks
    mfma_gemm<<<dim3(18, 144), 256, 0, stream>>>(xb, wt, nullptr, nullptr,
                                                 qkvb, QKV, 1);
    tv_pos1_kernel<<<dim3(10, B_ * NH), 256, 0, stream>>>(qkvb, pos_w, vtb, T1);
    attn_kernel<<<dim3(9, B_ * NH), 256, 0, stream>>>(qkvb, vtb, gating, aob);
    pos_stage2_kernel<<<dim3(B_ * NH, GW), 256, 0, stream>>>(T1, pos_w, gating, aob);
    // projection: fp32 out + bias, 64x128 tiles -> 864 blocks
    mfma_gemm<<<dim3(6, 144), 256, 0, stream>>>(aob, wt + 3 * we, bproj, out,
                                                nullptr, C_, 0);
}

// Round 10
// 248.854 us; speedup vs baseline: 1.1017x; 1.0488x over previous
//
#include <hip/hip_runtime.h>
#include <math.h>

#define B_ 16
#define N_ 576
#define C_ 768
#define NH 12
#define D_ 64
#define GW 24     // grid width/height (H = W = 24)
#define STR 68    // P/Q LDS row stride (ushorts)
#define QKV 2304  // fused QKV output row width

typedef unsigned short u16;
typedef __bf16 bf16x8 __attribute__((ext_vector_type(8)));
typedef float f32x4 __attribute__((ext_vector_type(4)));

__device__ __forceinline__ u16 f2bf(float f) {
    unsigned u = __builtin_bit_cast(unsigned, f);
    unsigned r = (u + 0x7FFFu + ((u >> 16) & 1u)) >> 16;
    return (u16)r;
}
__device__ __forceinline__ float bf2f(u16 b) {
    unsigned u = ((unsigned)b) << 16;
    return __builtin_bit_cast(float, u);
}

// 8B-granular LDS frag read (STR=68 rows are only 8B-aligned)
__device__ __forceinline__ bf16x8 ldsF8u(const u16* p) {
    union { uint2 u[2]; bf16x8 v; } t;
    t.u[0] = *(const uint2*)p;
    t.u[1] = *(const uint2*)(p + 4);
    return t.v;
}
// 16B-aligned LDS frag read
__device__ __forceinline__ bf16x8 ldsF8a(const u16* p) {
    union { uint4 u; bf16x8 v; } t;
    t.u = *(const uint4*)p;
    return t.v;
}

// async global->LDS, 16B/lane; LDS dest = wave-uniform base + lane*16
__device__ __forceinline__ void gload16(const u16* g, u16* l) {
    __builtin_amdgcn_global_load_lds(
        (const __attribute__((address_space(1))) void*)g,
        (__attribute__((address_space(3))) void*)l,
        16, 0, 0);
}

// ---------------------------------------------------------------------------
// prep kernel: z<4 -> W^T bf16 transpose (32x32 tile); z==4 -> x fp32->bf16
// ---------------------------------------------------------------------------
__global__ __launch_bounds__(256)
void prep_kernel(const float* __restrict__ x,
                 const float* __restrict__ w0, const float* __restrict__ w1,
                 const float* __restrict__ w2, const float* __restrict__ w3,
                 u16* __restrict__ xb, u16* __restrict__ wt_base)
{
    const int tid = threadIdx.x;
    if (blockIdx.z == 4) {
        const int flat = blockIdx.y * 24 + blockIdx.x;
#pragma unroll
        for (int it = 0; it < 12; ++it) {
            int idx = flat * 3072 + it * 256 + tid;
            float4 v = ((const float4*)x)[idx];
            u16 o[4] = {f2bf(v.x), f2bf(v.y), f2bf(v.z), f2bf(v.w)};
            *(uint2*)&xb[(size_t)idx * 4] = *(const uint2*)o;
        }
        return;
    }
    const float* srcs[4] = {w0, w1, w2, w3};
    const float* src = srcs[blockIdx.z];
    u16* dst = wt_base + (size_t)blockIdx.z * C_ * C_;
    __shared__ float t[32][33];
    const int bx = blockIdx.x * 32, by = blockIdx.y * 32;
    const int tx = tid & 31, ty = tid >> 5;
#pragma unroll
    for (int i = 0; i < 32; i += 8)
        t[ty + i][tx] = src[(size_t)(by + ty + i) * C_ + bx + tx];
    __syncthreads();
#pragma unroll
    for (int i = 0; i < 32; i += 8)
        dst[(size_t)(bx + ty + i) * C_ + by + tx] = f2bf(t[tx][ty + i]);
}

// ---------------------------------------------------------------------------
// bf16 MFMA GEMM: 64x128 tile, BK=64, XOR-swizzled staging LDS, 2592/864
// blocks for grid parallelism.  acc[i][j][r] = C[row=quad*4+r][col=l16].
// mode 0: fp32 [M][ldo] + bias.
// mode 1: bf16 [M][ldo] (Q section scaled); V-section blocks ALSO scatter
//         V^T into vtb [B,NH,D,N] (4 consecutive n packed per 8B store).
// ---------------------------------------------------------------------------
__global__ __launch_bounds__(256)
void mfma_gemm(const u16* __restrict__ A,
               const u16* __restrict__ BT,
               const float* __restrict__ bias,
               float* __restrict__ out,
               u16* __restrict__ outb,
               u16* __restrict__ vtb,
               int ldo, int mode)
{
    const int K = C_;
    __shared__ __align__(16) u16 As[64 * 64];    //  8 KB
    __shared__ __align__(16) u16 Bs[128 * 64];   // 16 KB
    const int tid = threadIdx.x;
    const int wave = tid >> 6, lane = tid & 63;
    const int quad = lane >> 4, l16 = lane & 15;
    const int wy = wave >> 1, wx = wave & 1;
    const int tm = blockIdx.y * 64, tn = blockIdx.x * 128;

    const int lr = lane >> 3;
    const int sc = ((lane & 7) ^ lr) * 8;

    f32x4 acc[2][4];
#pragma unroll
    for (int i = 0; i < 2; ++i)
#pragma unroll
        for (int j = 0; j < 4; ++j)
            acc[i][j] = (f32x4){0.f, 0.f, 0.f, 0.f};

    for (int k0 = 0; k0 < K; k0 += 64) {
        __syncthreads();
#pragma unroll
        for (int t = 0; t < 2; ++t) {
            const int rg = wave * 16 + t * 8;
            gload16(A + (size_t)(tm + rg + lr) * K + k0 + sc, &As[rg * 64]);
        }
#pragma unroll
        for (int t = 0; t < 4; ++t) {
            const int rg = wave * 32 + t * 8;
            gload16(BT + (size_t)(tn + rg + lr) * K + k0 + sc, &Bs[rg * 64]);
        }
        __syncthreads();

#pragma unroll
        for (int kh = 0; kh < 2; ++kh) {
            const int s = (kh * 4 + quad) ^ (l16 & 7);
            bf16x8 aA[2], bB[4];
#pragma unroll
            for (int i = 0; i < 2; ++i)
                aA[i] = ldsF8a(&As[(wy * 32 + i * 16 + l16) * 64 + s * 8]);
#pragma unroll
            for (int j = 0; j < 4; ++j)
                bB[j] = ldsF8a(&Bs[(wx * 64 + j * 16 + l16) * 64 + s * 8]);
#pragma unroll
            for (int i = 0; i < 2; ++i)
#pragma unroll
                for (int j = 0; j < 4; ++j)
                    acc[i][j] = __builtin_amdgcn_mfma_f32_16x16x32_bf16(aA[i], bB[j], acc[i][j], 0, 0, 0);
        }
    }

    if (mode == 0) {
#pragma unroll
        for (int i = 0; i < 2; ++i) {
#pragma unroll
            for (int r = 0; r < 4; ++r) {
                const int m = tm + wy * 32 + i * 16 + quad * 4 + r;
#pragma unroll
                for (int j = 0; j < 4; ++j) {
                    const int c = tn + wx * 64 + j * 16 + l16;
                    out[(size_t)m * ldo + c] = acc[i][j][r] + bias[c];
                }
            }
        }
    } else {
        const float scale = (tn < C_) ? 0.125f : 1.0f;
#pragma unroll
        for (int i = 0; i < 2; ++i) {
#pragma unroll
            for (int r = 0; r < 4; ++r) {
                const int m = tm + wy * 32 + i * 16 + quad * 4 + r;
#pragma unroll
                for (int j = 0; j < 4; ++j) {
                    const int c = tn + wx * 64 + j * 16 + l16;
                    outb[(size_t)m * ldo + c] = f2bf(acc[i][j][r] * scale);
                }
            }
        }
        if (tn >= 2 * C_) {
            // V-section: also write V^T (4 consecutive n packed per store)
            const int b = tm / N_;
#pragma unroll
            for (int i = 0; i < 2; ++i) {
                const int n0 = (tm % N_) + wy * 32 + i * 16 + quad * 4;
#pragma unroll
                for (int j = 0; j < 4; ++j) {
                    const int cc = tn - 2 * C_ + wx * 64 + j * 16 + l16;
                    const int hh = cc >> 6, dd = cc & 63;
                    u16 o[4];
#pragma unroll
                    for (int r = 0; r < 4; ++r) o[r] = f2bf(acc[i][j][r]);
                    *(uint2*)&vtb[(((size_t)b * NH + hh) * D_ + dd) * N_ + n0] =
                        *(const uint2*)o;
                }
            }
        }
    }
}

// ---------------------------------------------------------------------------
// pos stage 2 (x-axis + gate blend): U[n,d] = sum_mx ex[mx-nx]*T1[ny,mx,d];
// aob[b,n,h*64+d] += g/(Sx[nx]*Sy[ny]) * U   (RMW after attn wrote content)
// ---------------------------------------------------------------------------
__global__ __launch_bounds__(256)
void pos_stage2_kernel(const float* __restrict__ T1,
                       const float* __restrict__ pos_w,
                       const float* __restrict__ gating,
                       u16* __restrict__ aob)
{
    const int bh = blockIdx.x;      // 192
    const int ny = blockIdx.y;      // 24
    const int b = bh / NH, h = bh % NH;
    const int tid = threadIdx.x;
    __shared__ float T1s[GW * D_];  // 1536 floats = 384 float4
    __shared__ float ex[47];
    __shared__ float SxA[GW];
    __shared__ float Sy;
    const float w0 = pos_w[h], w1 = pos_w[NH + h], w2 = pos_w[2 * NH + h];

    const float* tsrc = T1 + ((size_t)bh * GW + ny) * GW * D_;
#pragma unroll
    for (int i = 0; i < 2; ++i) {
        int idx = i * 256 + tid;
        if (idx < 384) ((float4*)T1s)[idx] = ((const float4*)tsrc)[idx];
    }
    if (tid < 47) {
        float dx = (float)(tid - 23);
        ex[tid] = __expf(w0 * dx + w2 * dx * dx);
    }
    if (tid == 192) {
        float s = 0.f;
        for (int my = 0; my < GW; ++my) {
            float dy = (float)(my - ny);
            s += __expf(w1 * dy + w2 * dy * dy);
        }
        Sy = s;
    }
    __syncthreads();
    if (tid < GW) {
        float s = 0.f;
        for (int mx = 0; mx < GW; ++mx) s += ex[mx - tid + 23];
        SxA[tid] = s;
    }
    __syncthreads();
    if (tid >= 192) return;
    const int nx = tid >> 3, c = (tid & 7) << 3;

    float acc[8];
#pragma unroll
    for (int j = 0; j < 8; ++j) acc[j] = 0.f;
    for (int mx = 0; mx < GW; ++mx) {
        float e = ex[mx - nx + 23];
        float4 t0 = *(float4*)&T1s[mx * D_ + c];
        float4 t1 = *(float4*)&T1s[mx * D_ + c + 4];
        acc[0] += e * t0.x; acc[1] += e * t0.y; acc[2] += e * t0.z; acc[3] += e * t0.w;
        acc[4] += e * t1.x; acc[5] += e * t1.y; acc[6] += e * t1.z; acc[7] += e * t1.w;
    }
    const float g = 1.f / (1.f + __expf(-gating[h]));
    const float sc = g / (SxA[nx] * Sy);
    const int n = ny * GW + nx;
    u16* dst = aob + ((size_t)b * N_ + n) * C_ + h * D_ + c;
    u16 cur[8];
    *(uint4*)cur = *(const uint4*)dst;
    u16 o[8];
#pragma unroll
    for (int j = 0; j < 8; ++j) o[j] = f2bf(bf2f(cur[j]) + sc * acc[j]);
    *(uint4*)dst = *(const uint4*)o;
}

// ---------------------------------------------------------------------------
// Flash-style MFMA attention (content stream) + fused pos stage 1.
// blockIdx.x < 9: attention for 64 q-rows.  K/V tiles staged async via
// global_load_lds into XOR-swizzled unpadded [64][64] LDS (no register
// round-trip).  No online softmax (|s|<~4).  Writes (1-g)/l * O_c.
// blockIdx.x == 9: pos stage 1 (y-axis separable conv producing T1) — legal
// in the same kernel because T1 is only consumed by pos_stage2 (next launch).
// ---------------------------------------------------------------------------
__global__ __launch_bounds__(256)
void attn_kernel(const u16* __restrict__ qkvb,
                 const u16* __restrict__ vt,
                 const float* __restrict__ pos_w,
                 const float* __restrict__ gating,
                 u16* __restrict__ ao,
                 float* __restrict__ T1)
{
    const int qt = blockIdx.x;
    const int bh = blockIdx.y;
    const int b = bh / NH, h = bh % NH;
    const int tid = threadIdx.x;

    __shared__ __align__(16) u16 smem[2 * 64 * 64 + 64 * STR];  // 24.6 KB

    if (qt == 9) {
        // ---- pos stage 1: T1[bh,ny,mx,d] = sum_my ey[my-ny] * V[my*GW+mx][d]
        float* ey = (float*)smem;
        const float w1 = pos_w[NH + h], w2 = pos_w[2 * NH + h];
        if (tid < 47) {
            float dy = (float)(tid - 23);
            ey[tid] = __expf(w1 * dy + w2 * dy * dy);
        }
        __syncthreads();
        if (tid >= 192) return;
        const int mx = tid >> 3, c = (tid & 7) << 3;
        const u16* src = qkvb + (size_t)b * N_ * QKV + 2 * C_ + h * D_ + c;
#pragma unroll
        for (int np = 0; np < 3; ++np) {
            float acc[8][8];
#pragma unroll
            for (int q = 0; q < 8; ++q)
#pragma unroll
                for (int j = 0; j < 8; ++j) acc[q][j] = 0.f;
            for (int my = 0; my < GW; ++my) {
                union { uint4 u; u16 s[8]; } d;
                d.u = *(const uint4*)(src + (size_t)(my * GW + mx) * QKV);
                float vf[8];
#pragma unroll
                for (int j = 0; j < 8; ++j) vf[j] = bf2f(d.s[j]);
#pragma unroll
                for (int q = 0; q < 8; ++q) {
                    float e = ey[my - (np * 8 + q) + 23];
#pragma unroll
                    for (int j = 0; j < 8; ++j) acc[q][j] += e * vf[j];
                }
            }
#pragma unroll
            for (int q = 0; q < 8; ++q) {
                const int ny = np * 8 + q;
                float* dst = T1 + (((size_t)bh * GW + ny) * GW + mx) * D_ + c;
                *(float4*)dst       = *(float4*)&acc[q][0];
                *(float4*)(dst + 4) = *(float4*)&acc[q][4];
            }
        }
        return;
    }

    // ---- attention ----
    const int wave = tid >> 6, lane = tid & 63;
    const int quad = lane >> 4, l16 = lane & 15;
    u16* Kt = smem;                  // [64][64] swizzled  (K tile, rows=m')
    u16* Vs = smem + 4096;           // [64][64] swizzled  (V^T tile, rows=dd)
    u16* Pb = smem + 8192;           // [64][STR]  Q tile in prologue, then P

    const u16* qptr  = qkvb + ((size_t)b * N_ + qt * 64) * QKV + h * D_;
    const u16* kbase = qkvb + (size_t)b * N_ * QKV + C_ + h * D_;
    const u16* vbase = vt + (size_t)bh * D_ * N_;

    const int sr = tid >> 3;            // 0..31
    const int scol = (tid & 7) << 3;    // 0..56

    // stage Q into Pb (register path, padded rows)
#pragma unroll
    for (int p = 0; p < 2; ++p) {
        int r = p * 32 + sr;
        uint4 d = *(const uint4*)(qptr + (size_t)r * QKV + scol);
        *(uint2*)&Pb[r * STR + scol]     = make_uint2(d.x, d.y);
        *(uint2*)&Pb[r * STR + scol + 4] = make_uint2(d.z, d.w);
    }
    __syncthreads();

    const int arow = wave * 16 + l16;
    bf16x8 aq0 = ldsF8u(&Pb[arow * STR + quad * 8]);
    bf16x8 aq1 = ldsF8u(&Pb[arow * STR + 32 + quad * 8]);

    const int lr = lane >> 3;                 // staging row within 8-row group
    const int sg = ((lane & 7) ^ lr) * 8;     // swizzled source chunk (elems)
    const int x7 = l16 & 7;                   // read-side swizzle key

    f32x4 oc[4];
#pragma unroll
    for (int nt = 0; nt < 4; ++nt)
        oc[nt] = (f32x4){0.f, 0.f, 0.f, 0.f};
    float lrun[4] = {0.f, 0.f, 0.f, 0.f};

    for (int mt = 0; mt < 9; ++mt) {
        const int m0 = mt * 64;
        __syncthreads();   // prior-iter LDS reads done (iter0: Q-frag reads)
#pragma unroll
        for (int t = 0; t < 2; ++t) {
            const int rg = wave * 16 + t * 8;
            gload16(kbase + (size_t)(m0 + rg + lr) * QKV + sg, &Kt[rg * 64]);
            gload16(vbase + (size_t)(rg + lr) * N_ + m0 + sg, &Vs[rg * 64]);
        }
        __syncthreads();   // drains vmcnt (global_load_lds) for all waves

        // S = Q @ K^T
        f32x4 s[4];
#pragma unroll
        for (int nt = 0; nt < 4; ++nt) {
            const int ro = (nt * 16 + l16) * 64;
            bf16x8 b0 = ldsF8a(&Kt[ro + (quad ^ x7) * 8]);
            bf16x8 b1 = ldsF8a(&Kt[ro + ((quad + 4) ^ x7) * 8]);
            f32x4 z = (f32x4){0.f, 0.f, 0.f, 0.f};
            z = __builtin_amdgcn_mfma_f32_16x16x32_bf16(aq0, b0, z, 0, 0, 0);
            z = __builtin_amdgcn_mfma_f32_16x16x32_bf16(aq1, b1, z, 0, 0, 0);
            s[nt] = z;
        }

        // P = exp(S); per-lane partial row sums
#pragma unroll
        for (int r = 0; r < 4; ++r) {
            const int prow = (wave * 16 + quad * 4 + r) * STR;
            float e0 = __expf(s[0][r]);
            float e1 = __expf(s[1][r]);
            float e2 = __expf(s[2][r]);
            float e3 = __expf(s[3][r]);
            Pb[prow +  0 + l16] = f2bf(e0);
            Pb[prow + 16 + l16] = f2bf(e1);
            Pb[prow + 32 + l16] = f2bf(e2);
            Pb[prow + 48 + l16] = f2bf(e3);
            lrun[r] += (e0 + e1) + (e2 + e3);
        }
        asm volatile("s_waitcnt lgkmcnt(0)" ::: "memory");  // wave-local P drain

        // O_c += P @ V
#pragma unroll
        for (int ks = 0; ks < 2; ++ks) {
            bf16x8 ap = ldsF8u(&Pb[arow * STR + ks * 32 + quad * 8]);
#pragma unroll
            for (int nt = 0; nt < 4; ++nt) {
                const int ro = (nt * 16 + l16) * 64;
                bf16x8 bv = ldsF8a(&Vs[ro + ((ks * 4 + quad) ^ x7) * 8]);
                oc[nt] = __builtin_amdgcn_mfma_f32_16x16x32_bf16(ap, bv, oc[nt], 0, 0, 0);
            }
        }
    }

#pragma unroll
    for (int r = 0; r < 4; ++r) {
        lrun[r] += __shfl_xor(lrun[r], 1, 64);
        lrun[r] += __shfl_xor(lrun[r], 2, 64);
        lrun[r] += __shfl_xor(lrun[r], 4, 64);
        lrun[r] += __shfl_xor(lrun[r], 8, 64);
    }

    const float g = 1.f / (1.f + __expf(-gating[h]));
#pragma unroll
    for (int r = 0; r < 4; ++r) {
        const float sc = (1.f - g) / lrun[r];
        const int row = qt * 64 + wave * 16 + quad * 4 + r;
#pragma unroll
        for (int nt = 0; nt < 4; ++nt) {
            ao[((size_t)b * N_ + row) * C_ + h * D_ + nt * 16 + l16] =
                f2bf(oc[nt][r] * sc);
        }
    }
}

// ---------------------------------------------------------------------------
extern "C" void kernel_launch(void* const* d_in, const int* in_sizes, int n_in,
                              void* d_out, int out_size, void* d_ws, size_t ws_size,
                              hipStream_t stream)
{
    const float* x      = (const float*)d_in[0];
    const float* Wq     = (const float*)d_in[1];
    const float* Wk     = (const float*)d_in[2];
    const float* Wv     = (const float*)d_in[3];
    const float* Wproj  = (const float*)d_in[4];
    const float* bproj  = (const float*)d_in[5];
    const float* pos_w  = (const float*)d_in[6];
    const float* gating = (const float*)d_in[8];
    float* out = (float*)d_out;

    const size_t xe = (size_t)B_ * N_ * C_;        // 7,077,888
    const size_t we = (size_t)C_ * C_;             // 589,824
    const size_t qe = (size_t)B_ * N_ * QKV;       // 21,233,664
    u16* xb   = (u16*)d_ws;
    u16* wt   = xb + xe;            // packed [3072][768]: WqT|WkT|WvT|WprojT
    u16* qkvb = wt + 4 * we;        // [M][2304] bf16: Q | K | V
    u16* vtb  = qkvb + qe;          // [B,NH,D,N]
    u16* aob  = vtb + xe;           // [B,N,C] bf16 attn output
    float* T1 = (float*)(aob + xe); // [192][24][24][64] fp32 = 28.3 MB
    size_t need = (size_t)(3 * xe + 4 * we + qe) * sizeof(u16)
                + (size_t)B_ * NH * GW * GW * D_ * sizeof(float);  // ~118 MB
    if (ws_size < need) return;

    prep_kernel<<<dim3(24, 24, 5), 256, 0, stream>>>(x, Wq, Wk, Wv, Wproj, xb, wt);

    // fused QKV (+ V^T scatter): bf16 [9216][2304], 64x128 tiles, 2592 blocks
    mfma_gemm<<<dim3(18, 144), 256, 0, stream>>>(xb, wt, nullptr, nullptr,
                                                 qkvb, vtb, QKV, 1);
    // attention (x<9) + pos stage 1 (x==9)
    attn_kernel<<<dim3(10, B_ * NH), 256, 0, stream>>>(qkvb, vtb, pos_w, gating,
                                                       aob, T1);
    pos_stage2_kernel<<<dim3(B_ * NH, GW), 256, 0, stream>>>(T1, pos_w, gating, aob);
    // projection: fp32 out + bias, 64x128 tiles, 864 blocks
    mfma_gemm<<<dim3(6, 144), 256, 0, stream>>>(aob, wt + 3 * we, bproj, out,
                                                nullptr, nullptr, C_, 0);
}